// Round 14
// baseline (399.777 us; speedup 1.0000x reference)
//
#include <hip/hip_runtime.h>
#include <stdint.h>

#define D_IN 250
#define H_DIM 100
#define RPW 32            // rows per wave
#define NTHREADS 256      // 4 waves
#define BM (4*RPW)        // 128 rows per block

// ws layout: 588 fragments of 512 bf16 elems each.
// pass1 frag id = t*36 + ks*3 + g      (t 0..6, ks 0..11 [0-7 X, 8-11 Hs], g 0..2 [r,z,n])
// pass2 frag id = 252 + t*48 + ks*3+g  (ks 0..15 [0-7 X, 8-11 Hp, 12-15 HsN], g [z,r,hn])
#define P2_FRAG 252
#define TOTAL_E ((252 + 336) * 512)     // 301056 elems

#define NSLOT 6           // LDS ring slots (3 KB each); slot = global_step mod 6

typedef __bf16 bf16x8 __attribute__((ext_vector_type(8)));
typedef float f32x4 __attribute__((ext_vector_type(4)));

static __device__ __forceinline__ uint16_t f2bf(float f) {
  uint32_t u = __builtin_bit_cast(uint32_t, f);
  u = (u + 0x7FFFu + ((u >> 16) & 1u)) >> 16;
  return (uint16_t)u;
}
static __device__ __forceinline__ float bf2f(uint16_t h) {
  uint32_t u = ((uint32_t)h) << 16;
  return __builtin_bit_cast(float, u);
}
static __device__ __forceinline__ float sigmoidf_(float x) {
  return 1.0f / (1.0f + __expf(-x));
}
static __device__ __forceinline__ float tanhf_(float x) {
  return 2.0f / (1.0f + __expf(-2.0f * x)) - 1.0f;
}

// ---------------- weight prepack: fp32 -> bf16 B-fragment layout -------------
__global__ void prepack_kernel(const float* __restrict__ Wi, const float* __restrict__ Wh,
                               const float* __restrict__ W_z, const float* __restrict__ U_z,
                               const float* __restrict__ Us_z, const float* __restrict__ W_r,
                               const float* __restrict__ U_r, const float* __restrict__ Us_r,
                               const float* __restrict__ W_hn, const float* __restrict__ U_hn,
                               const float* __restrict__ Us_hn, const float* __restrict__ bi,
                               const float* __restrict__ bh, uint16_t* __restrict__ ws) {
  int idx = blockIdx.x * blockDim.x + threadIdx.x;
  if (idx >= TOTAL_E) return;
  int f = idx >> 9;
  int a = idx & 511;
  int lane = a >> 3, j = a & 7;
  int kloc = ((lane >> 4) << 3) + j;
  int cl = lane & 15;
  float val = 0.f;
  if (f < P2_FRAG) {
    int g = f % 3, ks = (f / 3) % 12, t = f / 36;
    int c = t * 16 + cl;
    if (c < H_DIM) {
      if (ks < 8) {
        int k = ks * 32 + kloc;
        if (k < D_IN)       val = Wi[(size_t)(g * H_DIM + c) * D_IN + k];
        else if (k == D_IN) val = bi[g * H_DIM + c];
      } else {
        int k = (ks - 8) * 32 + kloc;
        if (k < H_DIM)       val = Wh[(size_t)(g * H_DIM + c) * H_DIM + k];
        else if (k == H_DIM) val = bh[g * H_DIM + c];
      }
    }
  } else {
    int f2 = f - P2_FRAG;
    int g = f2 % 3, ks = (f2 / 3) % 16, t = f2 / 48;
    int c = t * 16 + cl;
    if (c < H_DIM) {
      if (ks < 8) {
        int k = ks * 32 + kloc;
        const float* W = g == 0 ? W_z : g == 1 ? W_r : W_hn;
        if (k < D_IN) val = W[(size_t)c * D_IN + k];
      } else if (ks < 12) {
        int k = (ks - 8) * 32 + kloc;
        const float* W = g == 0 ? U_z : g == 1 ? U_r : U_hn;
        if (k < H_DIM) val = W[(size_t)c * H_DIM + k];
      } else {
        int k = (ks - 12) * 32 + kloc;
        const float* W = g == 0 ? Us_z : g == 1 ? Us_r : Us_hn;
        if (k < H_DIM) val = W[(size_t)c * H_DIM + k];
      }
    }
  }
  ws[idx] = f2bf(val);
}

// ------------------------- A-fragment direct loaders -------------------------
static __device__ __forceinline__ bf16x8 xfrag(const float* __restrict__ xr, int ks, int q) {
  int c0 = ks * 32 + q * 8;
  bf16x8 a;
  if (c0 < 248) {
    #pragma unroll
    for (int i = 0; i < 4; ++i) {
      float2 f = *(const float2*)(xr + c0 + 2 * i);
      a[2 * i] = (__bf16)f.x; a[2 * i + 1] = (__bf16)f.y;
    }
  } else {                    // cols 248,249 valid; 250 = bias 1.0; rest 0
    float2 f = *(const float2*)(xr + 248);
    a[0] = (__bf16)f.x; a[1] = (__bf16)f.y; a[2] = (__bf16)1.0f;
    a[3] = (__bf16)0.0f; a[4] = (__bf16)0.0f; a[5] = (__bf16)0.0f;
    a[6] = (__bf16)0.0f; a[7] = (__bf16)0.0f;
  }
  return a;
}
static __device__ __forceinline__ bf16x8 hfrag(const float* __restrict__ hr, int ks, int q, float bias) {
  int c0 = ks * 32 + q * 8;
  bf16x8 a;
  #pragma unroll
  for (int i = 0; i < 8; ++i) a[i] = (__bf16)0.0f;
  if (c0 <= 88) {
    #pragma unroll
    for (int i = 0; i < 4; ++i) {
      float2 f = *(const float2*)(hr + c0 + 2 * i);
      a[2 * i] = (__bf16)f.x; a[2 * i + 1] = (__bf16)f.y;
    }
  } else if (c0 == 96) {      // cols 96..99 valid; 100 = bias; rest 0
    float2 f0 = *(const float2*)(hr + 96);
    float2 f1 = *(const float2*)(hr + 98);
    a[0] = (__bf16)f0.x; a[1] = (__bf16)f0.y; a[2] = (__bf16)f1.x; a[3] = (__bf16)f1.y;
    a[4] = (__bf16)bias;
  }
  return a;
}

#define MFMA(A, B, C) __builtin_amdgcn_mfma_f32_16x16x32_bf16((A), (B), (C), 0, 0, 0)

// frag-layout byte offset within a wave's lT slab (256 B per row)
static __device__ __forceinline__ int frag_bo(int h, int cl, int q, int ks) {
  int row = h * 16 + cl;
  return row * 256 + (((ks * 64) + q * 16) ^ ((row & 7) << 4));
}

// --------------- block-shared B ring: global -> LDS DMA ----------------------
typedef const __attribute__((address_space(1))) unsigned int* gp1_t;
typedef __attribute__((address_space(3))) unsigned int* lp3_t;

static __device__ __forceinline__ void gload(const uint16_t* gsrc, uint16_t* ldst) {
  __builtin_amdgcn_global_load_lds((gp1_t)gsrc, (lp3_t)ldst, 16, 0, 0);
}
#define WAIT_VM2   asm volatile("s_waitcnt vmcnt(2)" ::: "memory")
#define WAIT_VM0   asm volatile("s_waitcnt vmcnt(0)" ::: "memory")
#define WAIT_LGKM0 asm volatile("s_waitcnt lgkmcnt(0)" ::: "memory")
#define BAR        do { __builtin_amdgcn_s_barrier(); __builtin_amdgcn_sched_barrier(0); } while (0)

// ---------------------------- fused GRU kernel -------------------------------
// r12 schedule (6-slot ring, 2 K-steps/barrier, waves 0-2 issue, vmcnt(2)).
// Register cut vs r12: pa NOT held — pass 2 reads Hp frags from lT (read-only
// there). Pass 1 keeps ha in regs (r13's lT read raced the in-place HsNew
// update — fixed). Target: regs <= 170 -> 3 waves/SIMD; LDS 50 KB -> 3 blk/CU.
__global__ __launch_bounds__(NTHREADS, 3) void gru_fused(
    const float* __restrict__ x, const float* __restrict__ hp_g,
    const float* __restrict__ hs_g, const uint16_t* __restrict__ ws,
    float* __restrict__ out) {
  __shared__ __align__(16) uint16_t ldsT[4 * RPW * 128];   // 32 KB: Hs->HsNew, then Hp
  __shared__ __align__(16) uint16_t ring[NSLOT * 1536];    // 18 KB: 6 slots x 3 frags

  const int tid = threadIdx.x;
  const int lane = tid & 63, wid = tid >> 6;
  const int q = lane >> 4, cl = lane & 15;
  const int rowbase = blockIdx.x * BM + wid * RPW;
  uint16_t* lT = ldsT + wid * (RPW * 128);
  const uint16_t* wsl = ws + lane * 8;

  // ---- prologue: X and Hs frags held in regs; Hs also staged into lT ----
  bf16x8 xa[2][8], ha[2][4];
  #pragma unroll
  for (int h = 0; h < 2; ++h) {
    const float* xr = x + (size_t)(rowbase + h * 16 + cl) * D_IN;
    #pragma unroll
    for (int ks = 0; ks < 8; ++ks) xa[h][ks] = xfrag(xr, ks, q);
    const float* hr = hs_g + (size_t)(rowbase + h * 16 + cl) * H_DIM;
    #pragma unroll
    for (int ks = 0; ks < 4; ++ks) {
      ha[h][ks] = hfrag(hr, ks, q, 1.0f);
      *(bf16x8*)((char*)lT + frag_bo(h, cl, q, ks)) = ha[h][ks];  // cols 0..127
    }
  }

  // ring prologue: issue steps 0..3 into slots 0..3 (wave w loads gate w)
  if (wid < 3) {
    #pragma unroll
    for (int s = 0; s < 4; ++s)
      gload(wsl + (size_t)(s * 3 + wid) * 512, ring + s * 1536 + wid * 512);
    WAIT_VM2;                                  // steps 0,1 landed
  }
  BAR;

  // =========================== PASS 1 (GRU cell) ============================
  // 12 steps per t; 12 % 6 == 0 -> slots are compile-time static (= ks % 6).
  #pragma unroll 1
  for (int t = 0; t < 7; ++t) {
    f32x4 aR[2], aZ[2], aNi[2], aNh[2];
    #pragma unroll
    for (int h = 0; h < 2; ++h) { aR[h] = (f32x4)(0.f); aZ[h] = (f32x4)(0.f); aNi[h] = (f32x4)(0.f); aNh[h] = (f32x4)(0.f); }
    #pragma unroll
    for (int ks = 0; ks < 12; ks += 2) {
      // ds_read current steps ks, ks+1 (landing guaranteed 2 groups ago)
      const uint16_t* sp0 = ring + (ks % NSLOT) * 1536 + lane * 8;
      const uint16_t* sp1 = ring + ((ks + 1) % NSLOT) * 1536 + lane * 8;
      bf16x8 a0 = *(const bf16x8*)(sp0);
      bf16x8 a1 = *(const bf16x8*)(sp0 + 512);
      bf16x8 a2 = *(const bf16x8*)(sp0 + 1024);
      bf16x8 b0 = *(const bf16x8*)(sp1);
      bf16x8 b1 = *(const bf16x8*)(sp1 + 512);
      bf16x8 b2 = *(const bf16x8*)(sp1 + 1024);
      // issue DMA for steps ks+4, ks+5 (gate wid of each)
      if (wid < 3) {
        const int k4 = ks + 4, k5 = ks + 5;
        int f4 = (k4 < 12) ? (t * 36 + k4 * 3)
               : (t < 6 ? ((t + 1) * 36 + (k4 - 12) * 3) : (P2_FRAG + (k4 - 12) * 3));
        int f5 = (k5 < 12) ? (t * 36 + k5 * 3)
               : (t < 6 ? ((t + 1) * 36 + (k5 - 12) * 3) : (P2_FRAG + (k5 - 12) * 3));
        gload(wsl + (size_t)(f4 + wid) * 512, ring + (k4 % NSLOT) * 1536 + wid * 512);
        gload(wsl + (size_t)(f5 + wid) * 512, ring + (k5 % NSLOT) * 1536 + wid * 512);
      }
      __builtin_amdgcn_s_setprio(1);
      #pragma unroll
      for (int h = 0; h < 2; ++h) {
        bf16x8 av0 = (ks < 8) ? xa[h][ks] : ha[h][ks - 8];
        aR[h] = MFMA(av0, a0, aR[h]);
        aZ[h] = MFMA(av0, a1, aZ[h]);
        if (ks < 8) aNi[h] = MFMA(av0, a2, aNi[h]);
        else        aNh[h] = MFMA(av0, a2, aNh[h]);
        bf16x8 av1 = (ks + 1 < 8) ? xa[h][ks + 1] : ha[h][ks + 1 - 8];
        aR[h] = MFMA(av1, b0, aR[h]);
        aZ[h] = MFMA(av1, b1, aZ[h]);
        if (ks + 1 < 8) aNi[h] = MFMA(av1, b2, aNi[h]);
        else            aNh[h] = MFMA(av1, b2, aNh[h]);
      }
      __builtin_amdgcn_s_setprio(0);
      if (wid < 3) WAIT_VM2;                   // steps ks+2, ks+3 landed
      BAR;
    }
    // elementwise GRU cell -> HsNew written in place into lT (bf16)
    int c = t * 16 + cl;
    #pragma unroll
    for (int h = 0; h < 2; ++h) {
      #pragma unroll
      for (int r = 0; r < 4; ++r) {
        int row = h * 16 + q * 4 + r;
        int bo = row * 256 + ((c * 2) ^ ((row & 7) << 4));
        float hsp = bf2f(*(const uint16_t*)((const char*)lT + bo));
        float rr = sigmoidf_(aR[h][r]);
        float zz = sigmoidf_(aZ[h][r]);
        float nn = tanhf_(aNi[h][r] + rr * aNh[h][r]);
        float hsn = (1.f - zz) * nn + zz * hsp;
        *(uint16_t*)((char*)lT + bo) = f2bf(hsn);
      }
    }
  }

  // ---- boundary: HsNew frags -> na regs, then stage Hp into lT transiently ----
  bf16x8 na[2][4];
  #pragma unroll
  for (int h = 0; h < 2; ++h) {
    #pragma unroll
    for (int ks = 0; ks < 4; ++ks)
      na[h][ks] = *(const bf16x8*)((const char*)lT + frag_bo(h, cl, q, ks));
  }
  WAIT_LGKM0;                                  // na in regs before overwrite
  #pragma unroll
  for (int h = 0; h < 2; ++h) {
    const float* pr = hp_g + (size_t)(rowbase + h * 16 + cl) * H_DIM;
    #pragma unroll
    for (int ks = 0; ks < 4; ++ks) {
      bf16x8 f = hfrag(pr, ks, q, 0.0f);                 // transient build
      *(bf16x8*)((char*)lT + frag_bo(h, cl, q, ks)) = f;
    }
  }

  // =========================== PASS 2 (task head) ===========================
  // global step = 84 + t*16 + ks; 84 % 6 == 0; base drifts by 16 % 6 = 4 per t.
  int sb = 0;                                  // (t*16) mod 6
  #pragma unroll 1
  for (int t = 0; t < 7; ++t) {
    f32x4 aZ[2], aR[2], aNa[2], aNb[2];
    #pragma unroll
    for (int h = 0; h < 2; ++h) { aZ[h] = (f32x4)(0.f); aR[h] = (f32x4)(0.f); aNa[h] = (f32x4)(0.f); aNb[h] = (f32x4)(0.f); }
    #pragma unroll
    for (int ks = 0; ks < 16; ks += 2) {
      int s0 = sb + (ks % NSLOT);          if (s0 >= NSLOT) s0 -= NSLOT;
      int s1 = sb + ((ks + 1) % NSLOT);    if (s1 >= NSLOT) s1 -= NSLOT;
      const uint16_t* sp0 = ring + s0 * 1536 + lane * 8;
      const uint16_t* sp1 = ring + s1 * 1536 + lane * 8;
      bf16x8 a0 = *(const bf16x8*)(sp0);
      bf16x8 a1 = *(const bf16x8*)(sp0 + 512);
      bf16x8 a2 = *(const bf16x8*)(sp0 + 1024);
      bf16x8 b0 = *(const bf16x8*)(sp1);
      bf16x8 b1 = *(const bf16x8*)(sp1 + 512);
      bf16x8 b2 = *(const bf16x8*)(sp1 + 1024);
      if (wid < 3) {
        const int k4 = ks + 4, k5 = ks + 5;
        int f4 = (k4 < 16) ? (P2_FRAG + t * 48 + k4 * 3)
               : (t < 6 ? (P2_FRAG + (t + 1) * 48 + (k4 - 16) * 3) : P2_FRAG);   // tail clamp
        int f5 = (k5 < 16) ? (P2_FRAG + t * 48 + k5 * 3)
               : (t < 6 ? (P2_FRAG + (t + 1) * 48 + (k5 - 16) * 3) : P2_FRAG);   // tail clamp
        int s4 = sb + (k4 % NSLOT);        if (s4 >= NSLOT) s4 -= NSLOT;
        int s5 = sb + (k5 % NSLOT);        if (s5 >= NSLOT) s5 -= NSLOT;
        gload(wsl + (size_t)(f4 + wid) * 512, ring + s4 * 1536 + wid * 512);
        gload(wsl + (size_t)(f5 + wid) * 512, ring + s5 * 1536 + wid * 512);
      }
      __builtin_amdgcn_s_setprio(1);
      #pragma unroll
      for (int h = 0; h < 2; ++h) {
        bf16x8 av0 = (ks < 8) ? xa[h][ks]
                   : (ks < 12) ? *(const bf16x8*)((const char*)lT + frag_bo(h, cl, q, ks - 8))
                               : na[h][ks - 12];
        aZ[h] = MFMA(av0, a0, aZ[h]);
        aR[h] = MFMA(av0, a1, aR[h]);
        if (ks < 8)       aNa[h] = MFMA(av0, a2, aNa[h]);
        else if (ks < 12) aNb[h] = MFMA(av0, a2, aNb[h]);
        else              aNa[h] = MFMA(av0, a2, aNa[h]);
        bf16x8 av1 = (ks + 1 < 8) ? xa[h][ks + 1]
                   : (ks + 1 < 12) ? *(const bf16x8*)((const char*)lT + frag_bo(h, cl, q, ks + 1 - 8))
                                   : na[h][ks + 1 - 12];
        aZ[h] = MFMA(av1, b0, aZ[h]);
        aR[h] = MFMA(av1, b1, aR[h]);
        if (ks + 1 < 8)       aNa[h] = MFMA(av1, b2, aNa[h]);
        else if (ks + 1 < 12) aNb[h] = MFMA(av1, b2, aNb[h]);
        else                  aNa[h] = MFMA(av1, b2, aNa[h]);
      }
      __builtin_amdgcn_s_setprio(0);
      if (wid < 3) WAIT_VM2;
      BAR;
    }
    // elementwise + store (hpv from lT)
    int c = t * 16 + cl;
    bool valid = c < H_DIM;
    #pragma unroll
    for (int h = 0; h < 2; ++h) {
      #pragma unroll
      for (int r = 0; r < 4; ++r) {
        int row = h * 16 + q * 4 + r;
        int bo = row * 256 + ((c * 2) ^ ((row & 7) << 4));
        float hpv = bf2f(*(const uint16_t*)((const char*)lT + bo));
        float z2 = sigmoidf_(aZ[h][r]);
        float r2 = sigmoidf_(aR[h][r]);
        float nm = tanhf_(aNa[h][r] + r2 * aNb[h][r]);
        float hnew = (1.f - z2) * nm + z2 * hpv;
        if (valid) out[(size_t)(rowbase + row) * H_DIM + c] = hnew;
      }
    }
    sb += 4;
    if (sb >= NSLOT) sb -= NSLOT;
  }

  // drain outstanding DMAs (protect reallocated LDS from late landings)
  WAIT_VM0;
}

extern "C" void kernel_launch(void* const* d_in, const int* in_sizes, int n_in,
                              void* d_out, int out_size, void* d_ws, size_t ws_size,
                              hipStream_t stream) {
  const float* x    = (const float*)d_in[0];
  const float* h_p  = (const float*)d_in[1];
  const float* h_s  = (const float*)d_in[2];
  const float* Wi   = (const float*)d_in[3];
  const float* Wh   = (const float*)d_in[4];
  const float* bi   = (const float*)d_in[5];
  const float* bh   = (const float*)d_in[6];
  const float* W_z  = (const float*)d_in[7];
  const float* U_z  = (const float*)d_in[8];
  const float* Us_z = (const float*)d_in[9];
  const float* W_r  = (const float*)d_in[10];
  const float* U_r  = (const float*)d_in[11];
  const float* Us_r = (const float*)d_in[12];
  const float* W_hn = (const float*)d_in[13];
  const float* U_hn = (const float*)d_in[14];
  const float* Us_hn= (const float*)d_in[15];
  uint16_t* ws = (uint16_t*)d_ws;
  float* out = (float*)d_out;

  int rows = in_sizes[0] / D_IN;          // 262144
  prepack_kernel<<<(TOTAL_E + 255) / 256, 256, 0, stream>>>(
      Wi, Wh, W_z, U_z, Us_z, W_r, U_r, Us_r, W_hn, U_hn, Us_hn, bi, bh, ws);
  gru_fused<<<rows / BM, NTHREADS, 0, stream>>>(x, h_p, h_s, ws, out);
}

// Round 15
// 312.058 us; speedup vs baseline: 1.2811x; 1.2811x over previous
//
#include <hip/hip_runtime.h>
#include <stdint.h>

#define D_IN 250
#define H_DIM 100
#define RPW 32            // rows per wave
#define NTHREADS 128      // 2 waves
#define BM (2*RPW)        // 64 rows per block

// ws layout: 588 fragments of 512 bf16 elems each.
// pass1 frag id = t*36 + ks*3 + g      (t 0..6, ks 0..11 [0-7 X, 8-11 Hs], g 0..2 [r,z,n])
// pass2 frag id = 252 + t*48 + ks*3+g  (ks 0..15 [0-7 X, 8-11 Hp, 12-15 HsN], g [z,r,hn])
#define P2_FRAG 252
#define TOTAL_E ((252 + 336) * 512)     // 301056 elems

#define NSLOT 6           // LDS ring slots (3 KB each); slot = global_step mod 6

typedef __bf16 bf16x8 __attribute__((ext_vector_type(8)));
typedef float f32x4 __attribute__((ext_vector_type(4)));

static __device__ __forceinline__ uint16_t f2bf(float f) {
  uint32_t u = __builtin_bit_cast(uint32_t, f);
  u = (u + 0x7FFFu + ((u >> 16) & 1u)) >> 16;
  return (uint16_t)u;
}
static __device__ __forceinline__ float bf2f(uint16_t h) {
  uint32_t u = ((uint32_t)h) << 16;
  return __builtin_bit_cast(float, u);
}
static __device__ __forceinline__ float sigmoidf_(float x) {
  return 1.0f / (1.0f + __expf(-x));
}
static __device__ __forceinline__ float tanhf_(float x) {
  return 2.0f / (1.0f + __expf(-2.0f * x)) - 1.0f;
}

// ---------------- weight prepack: fp32 -> bf16 B-fragment layout -------------
__global__ void prepack_kernel(const float* __restrict__ Wi, const float* __restrict__ Wh,
                               const float* __restrict__ W_z, const float* __restrict__ U_z,
                               const float* __restrict__ Us_z, const float* __restrict__ W_r,
                               const float* __restrict__ U_r, const float* __restrict__ Us_r,
                               const float* __restrict__ W_hn, const float* __restrict__ U_hn,
                               const float* __restrict__ Us_hn, const float* __restrict__ bi,
                               const float* __restrict__ bh, uint16_t* __restrict__ ws) {
  int idx = blockIdx.x * blockDim.x + threadIdx.x;
  if (idx >= TOTAL_E) return;
  int f = idx >> 9;
  int a = idx & 511;
  int lane = a >> 3, j = a & 7;
  int kloc = ((lane >> 4) << 3) + j;
  int cl = lane & 15;
  float val = 0.f;
  if (f < P2_FRAG) {
    int g = f % 3, ks = (f / 3) % 12, t = f / 36;
    int c = t * 16 + cl;
    if (c < H_DIM) {
      if (ks < 8) {
        int k = ks * 32 + kloc;
        if (k < D_IN)       val = Wi[(size_t)(g * H_DIM + c) * D_IN + k];
        else if (k == D_IN) val = bi[g * H_DIM + c];
      } else {
        int k = (ks - 8) * 32 + kloc;
        if (k < H_DIM)       val = Wh[(size_t)(g * H_DIM + c) * H_DIM + k];
        else if (k == H_DIM) val = bh[g * H_DIM + c];
      }
    }
  } else {
    int f2 = f - P2_FRAG;
    int g = f2 % 3, ks = (f2 / 3) % 16, t = f2 / 48;
    int c = t * 16 + cl;
    if (c < H_DIM) {
      if (ks < 8) {
        int k = ks * 32 + kloc;
        const float* W = g == 0 ? W_z : g == 1 ? W_r : W_hn;
        if (k < D_IN) val = W[(size_t)c * D_IN + k];
      } else if (ks < 12) {
        int k = (ks - 8) * 32 + kloc;
        const float* W = g == 0 ? U_z : g == 1 ? U_r : U_hn;
        if (k < H_DIM) val = W[(size_t)c * H_DIM + k];
      } else {
        int k = (ks - 12) * 32 + kloc;
        const float* W = g == 0 ? Us_z : g == 1 ? Us_r : Us_hn;
        if (k < H_DIM) val = W[(size_t)c * H_DIM + k];
      }
    }
  }
  ws[idx] = f2bf(val);
}

// ------------------------- A-fragment direct loaders -------------------------
static __device__ __forceinline__ bf16x8 xfrag(const float* __restrict__ xr, int ks, int q) {
  int c0 = ks * 32 + q * 8;
  bf16x8 a;
  if (c0 < 248) {
    #pragma unroll
    for (int i = 0; i < 4; ++i) {
      float2 f = *(const float2*)(xr + c0 + 2 * i);
      a[2 * i] = (__bf16)f.x; a[2 * i + 1] = (__bf16)f.y;
    }
  } else {                    // cols 248,249 valid; 250 = bias 1.0; rest 0
    float2 f = *(const float2*)(xr + 248);
    a[0] = (__bf16)f.x; a[1] = (__bf16)f.y; a[2] = (__bf16)1.0f;
    a[3] = (__bf16)0.0f; a[4] = (__bf16)0.0f; a[5] = (__bf16)0.0f;
    a[6] = (__bf16)0.0f; a[7] = (__bf16)0.0f;
  }
  return a;
}
static __device__ __forceinline__ bf16x8 hfrag(const float* __restrict__ hr, int ks, int q, float bias) {
  int c0 = ks * 32 + q * 8;
  bf16x8 a;
  #pragma unroll
  for (int i = 0; i < 8; ++i) a[i] = (__bf16)0.0f;
  if (c0 <= 88) {
    #pragma unroll
    for (int i = 0; i < 4; ++i) {
      float2 f = *(const float2*)(hr + c0 + 2 * i);
      a[2 * i] = (__bf16)f.x; a[2 * i + 1] = (__bf16)f.y;
    }
  } else if (c0 == 96) {      // cols 96..99 valid; 100 = bias; rest 0
    float2 f0 = *(const float2*)(hr + 96);
    float2 f1 = *(const float2*)(hr + 98);
    a[0] = (__bf16)f0.x; a[1] = (__bf16)f0.y; a[2] = (__bf16)f1.x; a[3] = (__bf16)f1.y;
    a[4] = (__bf16)bias;
  }
  return a;
}

#define MFMA(A, B, C) __builtin_amdgcn_mfma_f32_16x16x32_bf16((A), (B), (C), 0, 0, 0)

// frag-layout byte offset within a wave's lT slab (256 B per row)
static __device__ __forceinline__ int frag_bo(int h, int cl, int q, int ks) {
  int row = h * 16 + cl;
  return row * 256 + (((ks * 64) + q * 16) ^ ((row & 7) << 4));
}

// --------------- block-shared B ring: global -> LDS DMA ----------------------
typedef const __attribute__((address_space(1))) unsigned int* gp1_t;
typedef __attribute__((address_space(3))) unsigned int* lp3_t;

static __device__ __forceinline__ void gload(const uint16_t* gsrc, uint16_t* ldst) {
  __builtin_amdgcn_global_load_lds((gp1_t)gsrc, (lp3_t)ldst, 16, 0, 0);
}
#define WAIT_VM3   asm volatile("s_waitcnt vmcnt(3)" ::: "memory")
#define WAIT_VM0   asm volatile("s_waitcnt vmcnt(0)" ::: "memory")
#define WAIT_LGKM0 asm volatile("s_waitcnt lgkmcnt(0)" ::: "memory")
#define BAR        do { __builtin_amdgcn_s_barrier(); __builtin_amdgcn_sched_barrier(0); } while (0)

// ---------------------------- fused GRU kernel -------------------------------
// r12 math/schedule with 2-WAVE blocks (BM=64): LDS 34 KB -> 4 blocks/CU, each
// barrier locksteps only 2 waves. Per group: wave0 DMAs step s+4 (3 frags),
// wave1 step s+5; both wait vmcnt(3). Slot = global_step mod 6.
__global__ __launch_bounds__(NTHREADS, 2) void gru_fused(
    const float* __restrict__ x, const float* __restrict__ hp_g,
    const float* __restrict__ hs_g, const uint16_t* __restrict__ ws,
    float* __restrict__ out) {
  __shared__ __align__(16) uint16_t ldsT[2 * RPW * 128];   // 16 KB: Hs->HsNew, then Hp
  __shared__ __align__(16) uint16_t ring[NSLOT * 1536];    // 18 KB: 6 slots x 3 frags

  const int tid = threadIdx.x;
  const int lane = tid & 63, wid = tid >> 6;               // wid in {0,1}
  const int q = lane >> 4, cl = lane & 15;
  const int rowbase = blockIdx.x * BM + wid * RPW;
  uint16_t* lT = ldsT + wid * (RPW * 128);
  const uint16_t* wsl = ws + lane * 8;

  // ---- prologue: X and Hs frags held in regs; Hs also staged into lT ----
  bf16x8 xa[2][8], ha[2][4];
  #pragma unroll
  for (int h = 0; h < 2; ++h) {
    const float* xr = x + (size_t)(rowbase + h * 16 + cl) * D_IN;
    #pragma unroll
    for (int ks = 0; ks < 8; ++ks) xa[h][ks] = xfrag(xr, ks, q);
    const float* hr = hs_g + (size_t)(rowbase + h * 16 + cl) * H_DIM;
    #pragma unroll
    for (int ks = 0; ks < 4; ++ks) {
      ha[h][ks] = hfrag(hr, ks, q, 1.0f);
      *(bf16x8*)((char*)lT + frag_bo(h, cl, q, ks)) = ha[h][ks];  // cols 0..127
    }
  }

  // ring prologue: wave0 issues steps {0,2}, wave1 {1,3} (3 frags each)
  {
    int s0 = wid;            // step 0 or 1
    int s1 = 2 + wid;        // step 2 or 3
    #pragma unroll
    for (int g = 0; g < 3; ++g)
      gload(wsl + (size_t)(s0 * 3 + g) * 512, ring + s0 * 1536 + g * 512);
    #pragma unroll
    for (int g = 0; g < 3; ++g)
      gload(wsl + (size_t)(s1 * 3 + g) * 512, ring + s1 * 1536 + g * 512);
    WAIT_VM3;                                  // own first step landed
  }
  BAR;                                          // union: steps 0,1 ready

  // =========================== PASS 1 (GRU cell) ============================
  // 12 steps per t; 12 % 6 == 0 -> slots are compile-time static (= ks % 6).
  #pragma unroll 1
  for (int t = 0; t < 7; ++t) {
    f32x4 aR[2], aZ[2], aNi[2], aNh[2];
    #pragma unroll
    for (int h = 0; h < 2; ++h) { aR[h] = (f32x4)(0.f); aZ[h] = (f32x4)(0.f); aNi[h] = (f32x4)(0.f); aNh[h] = (f32x4)(0.f); }
    #pragma unroll
    for (int ks = 0; ks < 12; ks += 2) {
      // ds_read current steps ks, ks+1 (landing guaranteed 2 groups ago)
      const uint16_t* sp0 = ring + (ks % NSLOT) * 1536 + lane * 8;
      const uint16_t* sp1 = ring + ((ks + 1) % NSLOT) * 1536 + lane * 8;
      bf16x8 a0 = *(const bf16x8*)(sp0);
      bf16x8 a1 = *(const bf16x8*)(sp0 + 512);
      bf16x8 a2 = *(const bf16x8*)(sp0 + 1024);
      bf16x8 b0 = *(const bf16x8*)(sp1);
      bf16x8 b1 = *(const bf16x8*)(sp1 + 512);
      bf16x8 b2 = *(const bf16x8*)(sp1 + 1024);
      // issue DMA: wave0 -> step ks+4 (all 3 frags), wave1 -> step ks+5
      {
        const int kI = ks + 4 + wid;
        int fI = (kI < 12) ? (t * 36 + kI * 3)
               : (t < 6 ? ((t + 1) * 36 + (kI - 12) * 3) : (P2_FRAG + (kI - 12) * 3));
        uint16_t* dst = ring + (kI % NSLOT) * 1536;
        #pragma unroll
        for (int g = 0; g < 3; ++g)
          gload(wsl + (size_t)(fI + g) * 512, dst + g * 512);
      }
      __builtin_amdgcn_s_setprio(1);
      #pragma unroll
      for (int h = 0; h < 2; ++h) {
        bf16x8 av0 = (ks < 8) ? xa[h][ks] : ha[h][ks - 8];
        aR[h] = MFMA(av0, a0, aR[h]);
        aZ[h] = MFMA(av0, a1, aZ[h]);
        if (ks < 8) aNi[h] = MFMA(av0, a2, aNi[h]);
        else        aNh[h] = MFMA(av0, a2, aNh[h]);
        bf16x8 av1 = (ks + 1 < 8) ? xa[h][ks + 1] : ha[h][ks + 1 - 8];
        aR[h] = MFMA(av1, b0, aR[h]);
        aZ[h] = MFMA(av1, b1, aZ[h]);
        if (ks + 1 < 8) aNi[h] = MFMA(av1, b2, aNi[h]);
        else            aNh[h] = MFMA(av1, b2, aNh[h]);
      }
      __builtin_amdgcn_s_setprio(0);
      WAIT_VM3;                                // own 2-groups-ago step landed
      BAR;                                     // union: steps ks+2, ks+3 ready
    }
    // elementwise GRU cell -> HsNew written in place into lT (bf16)
    int c = t * 16 + cl;
    #pragma unroll
    for (int h = 0; h < 2; ++h) {
      #pragma unroll
      for (int r = 0; r < 4; ++r) {
        int row = h * 16 + q * 4 + r;
        int bo = row * 256 + ((c * 2) ^ ((row & 7) << 4));
        float hsp = bf2f(*(const uint16_t*)((const char*)lT + bo));
        float rr = sigmoidf_(aR[h][r]);
        float zz = sigmoidf_(aZ[h][r]);
        float nn = tanhf_(aNi[h][r] + rr * aNh[h][r]);
        float hsn = (1.f - zz) * nn + zz * hsp;
        *(uint16_t*)((char*)lT + bo) = f2bf(hsn);
      }
    }
  }

  // ---- boundary: HsNew frags -> na regs, then stage Hp into lT transiently ----
  bf16x8 na[2][4];
  #pragma unroll
  for (int h = 0; h < 2; ++h) {
    #pragma unroll
    for (int ks = 0; ks < 4; ++ks)
      na[h][ks] = *(const bf16x8*)((const char*)lT + frag_bo(h, cl, q, ks));
  }
  WAIT_LGKM0;                                  // na in regs before overwrite
  #pragma unroll
  for (int h = 0; h < 2; ++h) {
    const float* pr = hp_g + (size_t)(rowbase + h * 16 + cl) * H_DIM;
    #pragma unroll
    for (int ks = 0; ks < 4; ++ks) {
      bf16x8 f = hfrag(pr, ks, q, 0.0f);                 // transient build
      *(bf16x8*)((char*)lT + frag_bo(h, cl, q, ks)) = f;
    }
  }

  // =========================== PASS 2 (task head) ===========================
  // global step = 84 + t*16 + ks; 84 % 6 == 0; base drifts by 16 % 6 = 4 per t.
  int sb = 0;                                  // (t*16) mod 6
  #pragma unroll 1
  for (int t = 0; t < 7; ++t) {
    f32x4 aZ[2], aR[2], aNa[2], aNb[2];
    #pragma unroll
    for (int h = 0; h < 2; ++h) { aZ[h] = (f32x4)(0.f); aR[h] = (f32x4)(0.f); aNa[h] = (f32x4)(0.f); aNb[h] = (f32x4)(0.f); }
    #pragma unroll
    for (int ks = 0; ks < 16; ks += 2) {
      int s0 = sb + (ks % NSLOT);          if (s0 >= NSLOT) s0 -= NSLOT;
      int s1 = sb + ((ks + 1) % NSLOT);    if (s1 >= NSLOT) s1 -= NSLOT;
      const uint16_t* sp0 = ring + s0 * 1536 + lane * 8;
      const uint16_t* sp1 = ring + s1 * 1536 + lane * 8;
      bf16x8 a0 = *(const bf16x8*)(sp0);
      bf16x8 a1 = *(const bf16x8*)(sp0 + 512);
      bf16x8 a2 = *(const bf16x8*)(sp0 + 1024);
      bf16x8 b0 = *(const bf16x8*)(sp1);
      bf16x8 b1 = *(const bf16x8*)(sp1 + 512);
      bf16x8 b2 = *(const bf16x8*)(sp1 + 1024);
      // issue DMA: wave0 -> step ks+4, wave1 -> step ks+5
      {
        const int kI = ks + 4 + wid;
        int fI = (kI < 16) ? (P2_FRAG + t * 48 + kI * 3)
               : (t < 6 ? (P2_FRAG + (t + 1) * 48 + (kI - 16) * 3) : P2_FRAG);   // tail clamp
        int sI = sb + (kI % NSLOT);        if (sI >= NSLOT) sI -= NSLOT;
        uint16_t* dst = ring + sI * 1536;
        #pragma unroll
        for (int g = 0; g < 3; ++g)
          gload(wsl + (size_t)(fI + g) * 512, dst + g * 512);
      }
      __builtin_amdgcn_s_setprio(1);
      #pragma unroll
      for (int h = 0; h < 2; ++h) {
        bf16x8 av0 = (ks < 8) ? xa[h][ks]
                   : (ks < 12) ? *(const bf16x8*)((const char*)lT + frag_bo(h, cl, q, ks - 8))
                               : na[h][ks - 12];
        aZ[h] = MFMA(av0, a0, aZ[h]);
        aR[h] = MFMA(av0, a1, aR[h]);
        if (ks < 8)       aNa[h] = MFMA(av0, a2, aNa[h]);
        else if (ks < 12) aNb[h] = MFMA(av0, a2, aNb[h]);
        else              aNa[h] = MFMA(av0, a2, aNa[h]);
        bf16x8 av1 = (ks + 1 < 8) ? xa[h][ks + 1]
                   : (ks + 1 < 12) ? *(const bf16x8*)((const char*)lT + frag_bo(h, cl, q, ks + 1 - 8))
                                   : na[h][ks + 1 - 12];
        aZ[h] = MFMA(av1, b0, aZ[h]);
        aR[h] = MFMA(av1, b1, aR[h]);
        if (ks + 1 < 8)       aNa[h] = MFMA(av1, b2, aNa[h]);
        else if (ks + 1 < 12) aNb[h] = MFMA(av1, b2, aNb[h]);
        else                  aNa[h] = MFMA(av1, b2, aNa[h]);
      }
      __builtin_amdgcn_s_setprio(0);
      WAIT_VM3;
      BAR;
    }
    // elementwise + store (hpv from lT)
    int c = t * 16 + cl;
    bool valid = c < H_DIM;
    #pragma unroll
    for (int h = 0; h < 2; ++h) {
      #pragma unroll
      for (int r = 0; r < 4; ++r) {
        int row = h * 16 + q * 4 + r;
        int bo = row * 256 + ((c * 2) ^ ((row & 7) << 4));
        float hpv = bf2f(*(const uint16_t*)((const char*)lT + bo));
        float z2 = sigmoidf_(aZ[h][r]);
        float r2 = sigmoidf_(aR[h][r]);
        float nm = tanhf_(aNa[h][r] + r2 * aNb[h][r]);
        float hnew = (1.f - z2) * nm + z2 * hpv;
        if (valid) out[(size_t)(rowbase + row) * H_DIM + c] = hnew;
      }
    }
    sb += 4;
    if (sb >= NSLOT) sb -= NSLOT;
  }

  // drain outstanding DMAs (protect reallocated LDS from late landings)
  WAIT_VM0;
}

extern "C" void kernel_launch(void* const* d_in, const int* in_sizes, int n_in,
                              void* d_out, int out_size, void* d_ws, size_t ws_size,
                              hipStream_t stream) {
  const float* x    = (const float*)d_in[0];
  const float* h_p  = (const float*)d_in[1];
  const float* h_s  = (const float*)d_in[2];
  const float* Wi   = (const float*)d_in[3];
  const float* Wh   = (const float*)d_in[4];
  const float* bi   = (const float*)d_in[5];
  const float* bh   = (const float*)d_in[6];
  const float* W_z  = (const float*)d_in[7];
  const float* U_z  = (const float*)d_in[8];
  const float* Us_z = (const float*)d_in[9];
  const float* W_r  = (const float*)d_in[10];
  const float* U_r  = (const float*)d_in[11];
  const float* Us_r = (const float*)d_in[12];
  const float* W_hn = (const float*)d_in[13];
  const float* U_hn = (const float*)d_in[14];
  const float* Us_hn= (const float*)d_in[15];
  uint16_t* ws = (uint16_t*)d_ws;
  float* out = (float*)d_out;

  int rows = in_sizes[0] / D_IN;          // 262144
  prepack_kernel<<<(TOTAL_E + 255) / 256, 256, 0, stream>>>(
      Wi, Wh, W_z, U_z, Us_z, W_r, U_r, Us_r, W_hn, U_hn, Us_hn, bi, bh, ws);
  gru_fused<<<rows / BM, NTHREADS, 0, stream>>>(x, h_p, h_s, ws, out);
}

// Round 16
// 279.173 us; speedup vs baseline: 1.4320x; 1.1178x over previous
//
#include <hip/hip_runtime.h>
#include <stdint.h>

#define D_IN 250
#define H_DIM 100
#define RPW 16            // rows per wave (halved: register cut -> 4 waves/SIMD)
#define NTHREADS 256      // 4 waves
#define BM (4*RPW)        // 64 rows per block

// ws layout: 588 fragments of 512 bf16 elems each.
// pass1 frag id = t*36 + ks*3 + g      (t 0..6, ks 0..11 [0-7 X, 8-11 Hs], g 0..2 [r,z,n])
// pass2 frag id = 252 + t*48 + ks*3+g  (ks 0..15 [0-7 X, 8-11 Hp, 12-15 HsN], g [z,r,hn])
#define P2_FRAG 252
#define TOTAL_E ((252 + 336) * 512)     // 301056 elems

#define NSLOT 6           // LDS ring slots (3 KB each); slot = global_step mod 6

typedef __bf16 bf16x8 __attribute__((ext_vector_type(8)));
typedef float f32x4 __attribute__((ext_vector_type(4)));

static __device__ __forceinline__ uint16_t f2bf(float f) {
  uint32_t u = __builtin_bit_cast(uint32_t, f);
  u = (u + 0x7FFFu + ((u >> 16) & 1u)) >> 16;
  return (uint16_t)u;
}
static __device__ __forceinline__ float bf2f(uint16_t h) {
  uint32_t u = ((uint32_t)h) << 16;
  return __builtin_bit_cast(float, u);
}
static __device__ __forceinline__ float sigmoidf_(float x) {
  return 1.0f / (1.0f + __expf(-x));
}
static __device__ __forceinline__ float tanhf_(float x) {
  return 2.0f / (1.0f + __expf(-2.0f * x)) - 1.0f;
}

// ---------------- weight prepack: fp32 -> bf16 B-fragment layout -------------
__global__ void prepack_kernel(const float* __restrict__ Wi, const float* __restrict__ Wh,
                               const float* __restrict__ W_z, const float* __restrict__ U_z,
                               const float* __restrict__ Us_z, const float* __restrict__ W_r,
                               const float* __restrict__ U_r, const float* __restrict__ Us_r,
                               const float* __restrict__ W_hn, const float* __restrict__ U_hn,
                               const float* __restrict__ Us_hn, const float* __restrict__ bi,
                               const float* __restrict__ bh, uint16_t* __restrict__ ws) {
  int idx = blockIdx.x * blockDim.x + threadIdx.x;
  if (idx >= TOTAL_E) return;
  int f = idx >> 9;
  int a = idx & 511;
  int lane = a >> 3, j = a & 7;
  int kloc = ((lane >> 4) << 3) + j;
  int cl = lane & 15;
  float val = 0.f;
  if (f < P2_FRAG) {
    int g = f % 3, ks = (f / 3) % 12, t = f / 36;
    int c = t * 16 + cl;
    if (c < H_DIM) {
      if (ks < 8) {
        int k = ks * 32 + kloc;
        if (k < D_IN)       val = Wi[(size_t)(g * H_DIM + c) * D_IN + k];
        else if (k == D_IN) val = bi[g * H_DIM + c];
      } else {
        int k = (ks - 8) * 32 + kloc;
        if (k < H_DIM)       val = Wh[(size_t)(g * H_DIM + c) * H_DIM + k];
        else if (k == H_DIM) val = bh[g * H_DIM + c];
      }
    }
  } else {
    int f2 = f - P2_FRAG;
    int g = f2 % 3, ks = (f2 / 3) % 16, t = f2 / 48;
    int c = t * 16 + cl;
    if (c < H_DIM) {
      if (ks < 8) {
        int k = ks * 32 + kloc;
        const float* W = g == 0 ? W_z : g == 1 ? W_r : W_hn;
        if (k < D_IN) val = W[(size_t)c * D_IN + k];
      } else if (ks < 12) {
        int k = (ks - 8) * 32 + kloc;
        const float* W = g == 0 ? U_z : g == 1 ? U_r : U_hn;
        if (k < H_DIM) val = W[(size_t)c * H_DIM + k];
      } else {
        int k = (ks - 12) * 32 + kloc;
        const float* W = g == 0 ? Us_z : g == 1 ? Us_r : Us_hn;
        if (k < H_DIM) val = W[(size_t)c * H_DIM + k];
      }
    }
  }
  ws[idx] = f2bf(val);
}

// ------------------------- A-fragment direct loaders -------------------------
static __device__ __forceinline__ bf16x8 xfrag(const float* __restrict__ xr, int ks, int q) {
  int c0 = ks * 32 + q * 8;
  bf16x8 a;
  if (c0 < 248) {
    #pragma unroll
    for (int i = 0; i < 4; ++i) {
      float2 f = *(const float2*)(xr + c0 + 2 * i);
      a[2 * i] = (__bf16)f.x; a[2 * i + 1] = (__bf16)f.y;
    }
  } else {                    // cols 248,249 valid; 250 = bias 1.0; rest 0
    float2 f = *(const float2*)(xr + 248);
    a[0] = (__bf16)f.x; a[1] = (__bf16)f.y; a[2] = (__bf16)1.0f;
    a[3] = (__bf16)0.0f; a[4] = (__bf16)0.0f; a[5] = (__bf16)0.0f;
    a[6] = (__bf16)0.0f; a[7] = (__bf16)0.0f;
  }
  return a;
}
static __device__ __forceinline__ bf16x8 hfrag(const float* __restrict__ hr, int ks, int q, float bias) {
  int c0 = ks * 32 + q * 8;
  bf16x8 a;
  #pragma unroll
  for (int i = 0; i < 8; ++i) a[i] = (__bf16)0.0f;
  if (c0 <= 88) {
    #pragma unroll
    for (int i = 0; i < 4; ++i) {
      float2 f = *(const float2*)(hr + c0 + 2 * i);
      a[2 * i] = (__bf16)f.x; a[2 * i + 1] = (__bf16)f.y;
    }
  } else if (c0 == 96) {      // cols 96..99 valid; 100 = bias; rest 0
    float2 f0 = *(const float2*)(hr + 96);
    float2 f1 = *(const float2*)(hr + 98);
    a[0] = (__bf16)f0.x; a[1] = (__bf16)f0.y; a[2] = (__bf16)f1.x; a[3] = (__bf16)f1.y;
    a[4] = (__bf16)bias;
  }
  return a;
}

#define MFMA(A, B, C) __builtin_amdgcn_mfma_f32_16x16x32_bf16((A), (B), (C), 0, 0, 0)

// frag-layout byte offset within a wave's lT slab (16 rows x 256 B)
static __device__ __forceinline__ int frag_bo(int cl, int q, int ks) {
  return cl * 256 + (((ks * 64) + q * 16) ^ ((cl & 7) << 4));
}

// --------------- block-shared B ring: global -> LDS DMA ----------------------
typedef const __attribute__((address_space(1))) unsigned int* gp1_t;
typedef __attribute__((address_space(3))) unsigned int* lp3_t;

static __device__ __forceinline__ void gload(const uint16_t* gsrc, uint16_t* ldst) {
  __builtin_amdgcn_global_load_lds((gp1_t)gsrc, (lp3_t)ldst, 16, 0, 0);
}
#define WAIT_VM2   asm volatile("s_waitcnt vmcnt(2)" ::: "memory")
#define WAIT_VM0   asm volatile("s_waitcnt vmcnt(0)" ::: "memory")
#define WAIT_LGKM0 asm volatile("s_waitcnt lgkmcnt(0)" ::: "memory")
#define BAR        do { __builtin_amdgcn_s_barrier(); __builtin_amdgcn_sched_barrier(0); } while (0)

// ---------------------------- fused GRU kernel -------------------------------
// r12 schedule (6-slot ring, 2 K-steps/barrier, waves 0-2 issue, vmcnt(2)) at
// RPW=16: per-wave state ~110 regs -> 4 waves/SIMD; LDS 34 KB -> 4 blocks/CU.
__global__ __launch_bounds__(NTHREADS, 4) void gru_fused(
    const float* __restrict__ x, const float* __restrict__ hp_g,
    const float* __restrict__ hs_g, const uint16_t* __restrict__ ws,
    float* __restrict__ out) {
  __shared__ __align__(16) uint16_t ldsT[4 * RPW * 128];   // 16 KB: Hs->HsNew, then Hp
  __shared__ __align__(16) uint16_t ring[NSLOT * 1536];    // 18 KB: 6 slots x 3 frags

  const int tid = threadIdx.x;
  const int lane = tid & 63, wid = tid >> 6;
  const int q = lane >> 4, cl = lane & 15;
  const int rowbase = blockIdx.x * BM + wid * RPW;
  uint16_t* lT = ldsT + wid * (RPW * 128);
  const uint16_t* wsl = ws + lane * 8;

  // ---- prologue: X and Hs frags held in regs; Hs also staged into lT ----
  bf16x8 xa[8], ha[4];
  {
    const float* xr = x + (size_t)(rowbase + cl) * D_IN;
    #pragma unroll
    for (int ks = 0; ks < 8; ++ks) xa[ks] = xfrag(xr, ks, q);
    const float* hr = hs_g + (size_t)(rowbase + cl) * H_DIM;
    #pragma unroll
    for (int ks = 0; ks < 4; ++ks) {
      ha[ks] = hfrag(hr, ks, q, 1.0f);
      *(bf16x8*)((char*)lT + frag_bo(cl, q, ks)) = ha[ks];  // cols 0..127
    }
  }

  // ring prologue: issue steps 0..3 into slots 0..3 (wave w loads gate w)
  if (wid < 3) {
    #pragma unroll
    for (int s = 0; s < 4; ++s)
      gload(wsl + (size_t)(s * 3 + wid) * 512, ring + s * 1536 + wid * 512);
    WAIT_VM2;                                  // steps 0,1 landed
  }
  BAR;

  // =========================== PASS 1 (GRU cell) ============================
  // 12 steps per t; 12 % 6 == 0 -> slots are compile-time static (= ks % 6).
  #pragma unroll 1
  for (int t = 0; t < 7; ++t) {
    f32x4 aR = (f32x4)(0.f), aZ = (f32x4)(0.f), aNi = (f32x4)(0.f), aNh = (f32x4)(0.f);
    #pragma unroll
    for (int ks = 0; ks < 12; ks += 2) {
      // ds_read current steps ks, ks+1 (landing guaranteed 2 groups ago)
      const uint16_t* sp0 = ring + (ks % NSLOT) * 1536 + lane * 8;
      const uint16_t* sp1 = ring + ((ks + 1) % NSLOT) * 1536 + lane * 8;
      bf16x8 a0 = *(const bf16x8*)(sp0);
      bf16x8 a1 = *(const bf16x8*)(sp0 + 512);
      bf16x8 a2 = *(const bf16x8*)(sp0 + 1024);
      bf16x8 b0 = *(const bf16x8*)(sp1);
      bf16x8 b1 = *(const bf16x8*)(sp1 + 512);
      bf16x8 b2 = *(const bf16x8*)(sp1 + 1024);
      // issue DMA for steps ks+4, ks+5 (gate wid of each)
      if (wid < 3) {
        const int k4 = ks + 4, k5 = ks + 5;
        int f4 = (k4 < 12) ? (t * 36 + k4 * 3)
               : (t < 6 ? ((t + 1) * 36 + (k4 - 12) * 3) : (P2_FRAG + (k4 - 12) * 3));
        int f5 = (k5 < 12) ? (t * 36 + k5 * 3)
               : (t < 6 ? ((t + 1) * 36 + (k5 - 12) * 3) : (P2_FRAG + (k5 - 12) * 3));
        gload(wsl + (size_t)(f4 + wid) * 512, ring + (k4 % NSLOT) * 1536 + wid * 512);
        gload(wsl + (size_t)(f5 + wid) * 512, ring + (k5 % NSLOT) * 1536 + wid * 512);
      }
      __builtin_amdgcn_s_setprio(1);
      {
        bf16x8 av0 = (ks < 8) ? xa[ks] : ha[ks - 8];
        aR = MFMA(av0, a0, aR);
        aZ = MFMA(av0, a1, aZ);
        if (ks < 8) aNi = MFMA(av0, a2, aNi);
        else        aNh = MFMA(av0, a2, aNh);
        bf16x8 av1 = (ks + 1 < 8) ? xa[ks + 1] : ha[ks + 1 - 8];
        aR = MFMA(av1, b0, aR);
        aZ = MFMA(av1, b1, aZ);
        if (ks + 1 < 8) aNi = MFMA(av1, b2, aNi);
        else            aNh = MFMA(av1, b2, aNh);
      }
      __builtin_amdgcn_s_setprio(0);
      if (wid < 3) WAIT_VM2;                   // steps ks+2, ks+3 landed
      BAR;
    }
    // elementwise GRU cell -> HsNew written in place into lT (bf16)
    int c = t * 16 + cl;
    #pragma unroll
    for (int r = 0; r < 4; ++r) {
      int row = q * 4 + r;
      int bo = row * 256 + ((c * 2) ^ ((row & 7) << 4));
      float hsp = bf2f(*(const uint16_t*)((const char*)lT + bo));
      float rr = sigmoidf_(aR[r]);
      float zz = sigmoidf_(aZ[r]);
      float nn = tanhf_(aNi[r] + rr * aNh[r]);
      float hsn = (1.f - zz) * nn + zz * hsp;
      *(uint16_t*)((char*)lT + bo) = f2bf(hsn);
    }
  }

  // ---- boundary: HsNew frags -> na regs, then stage Hp into lT transiently ----
  bf16x8 na[4];
  #pragma unroll
  for (int ks = 0; ks < 4; ++ks)
    na[ks] = *(const bf16x8*)((const char*)lT + frag_bo(cl, q, ks));
  WAIT_LGKM0;                                  // na in regs before overwrite
  {
    const float* pr = hp_g + (size_t)(rowbase + cl) * H_DIM;
    #pragma unroll
    for (int ks = 0; ks < 4; ++ks) {
      bf16x8 f = hfrag(pr, ks, q, 0.0f);                 // transient build
      *(bf16x8*)((char*)lT + frag_bo(cl, q, ks)) = f;
    }
  }

  // =========================== PASS 2 (task head) ===========================
  // global step = 84 + t*16 + ks; 84 % 6 == 0; base drifts by 16 % 6 = 4 per t.
  int sb = 0;                                  // (t*16) mod 6
  #pragma unroll 1
  for (int t = 0; t < 7; ++t) {
    f32x4 aZ = (f32x4)(0.f), aR = (f32x4)(0.f), aNa = (f32x4)(0.f), aNb = (f32x4)(0.f);
    #pragma unroll
    for (int ks = 0; ks < 16; ks += 2) {
      int s0 = sb + (ks % NSLOT);          if (s0 >= NSLOT) s0 -= NSLOT;
      int s1 = sb + ((ks + 1) % NSLOT);    if (s1 >= NSLOT) s1 -= NSLOT;
      const uint16_t* sp0 = ring + s0 * 1536 + lane * 8;
      const uint16_t* sp1 = ring + s1 * 1536 + lane * 8;
      bf16x8 a0 = *(const bf16x8*)(sp0);
      bf16x8 a1 = *(const bf16x8*)(sp0 + 512);
      bf16x8 a2 = *(const bf16x8*)(sp0 + 1024);
      bf16x8 b0 = *(const bf16x8*)(sp1);
      bf16x8 b1 = *(const bf16x8*)(sp1 + 512);
      bf16x8 b2 = *(const bf16x8*)(sp1 + 1024);
      if (wid < 3) {
        const int k4 = ks + 4, k5 = ks + 5;
        int f4 = (k4 < 16) ? (P2_FRAG + t * 48 + k4 * 3)
               : (t < 6 ? (P2_FRAG + (t + 1) * 48 + (k4 - 16) * 3) : P2_FRAG);   // tail clamp
        int f5 = (k5 < 16) ? (P2_FRAG + t * 48 + k5 * 3)
               : (t < 6 ? (P2_FRAG + (t + 1) * 48 + (k5 - 16) * 3) : P2_FRAG);   // tail clamp
        int s4 = sb + (k4 % NSLOT);        if (s4 >= NSLOT) s4 -= NSLOT;
        int s5 = sb + (k5 % NSLOT);        if (s5 >= NSLOT) s5 -= NSLOT;
        gload(wsl + (size_t)(f4 + wid) * 512, ring + s4 * 1536 + wid * 512);
        gload(wsl + (size_t)(f5 + wid) * 512, ring + s5 * 1536 + wid * 512);
      }
      __builtin_amdgcn_s_setprio(1);
      {
        bf16x8 av0 = (ks < 8) ? xa[ks]
                   : (ks < 12) ? *(const bf16x8*)((const char*)lT + frag_bo(cl, q, ks - 8))
                               : na[ks - 12];
        aZ = MFMA(av0, a0, aZ);
        aR = MFMA(av0, a1, aR);
        if (ks < 8)       aNa = MFMA(av0, a2, aNa);
        else if (ks < 12) aNb = MFMA(av0, a2, aNb);
        else              aNa = MFMA(av0, a2, aNa);
        bf16x8 av1 = (ks + 1 < 8) ? xa[ks + 1]
                   : (ks + 1 < 12) ? *(const bf16x8*)((const char*)lT + frag_bo(cl, q, ks + 1 - 8))
                                   : na[ks + 1 - 12];
        aZ = MFMA(av1, b0, aZ);
        aR = MFMA(av1, b1, aR);
        if (ks + 1 < 8)       aNa = MFMA(av1, b2, aNa);
        else if (ks + 1 < 12) aNb = MFMA(av1, b2, aNb);
        else                  aNa = MFMA(av1, b2, aNa);
      }
      __builtin_amdgcn_s_setprio(0);
      if (wid < 3) WAIT_VM2;
      BAR;
    }
    // elementwise + store (hpv from lT)
    int c = t * 16 + cl;
    bool valid = c < H_DIM;
    #pragma unroll
    for (int r = 0; r < 4; ++r) {
      int row = q * 4 + r;
      int bo = row * 256 + ((c * 2) ^ ((row & 7) << 4));
      float hpv = bf2f(*(const uint16_t*)((const char*)lT + bo));
      float z2 = sigmoidf_(aZ[r]);
      float r2 = sigmoidf_(aR[r]);
      float nm = tanhf_(aNa[r] + r2 * aNb[r]);
      float hnew = (1.f - z2) * nm + z2 * hpv;
      if (valid) out[(size_t)(rowbase + row) * H_DIM + c] = hnew;
    }
    sb += 4;
    if (sb >= NSLOT) sb -= NSLOT;
  }

  // drain outstanding DMAs (protect reallocated LDS from late landings)
  WAIT_VM0;
}

extern "C" void kernel_launch(void* const* d_in, const int* in_sizes, int n_in,
                              void* d_out, int out_size, void* d_ws, size_t ws_size,
                              hipStream_t stream) {
  const float* x    = (const float*)d_in[0];
  const float* h_p  = (const float*)d_in[1];
  const float* h_s  = (const float*)d_in[2];
  const float* Wi   = (const float*)d_in[3];
  const float* Wh   = (const float*)d_in[4];
  const float* bi   = (const float*)d_in[5];
  const float* bh   = (const float*)d_in[6];
  const float* W_z  = (const float*)d_in[7];
  const float* U_z  = (const float*)d_in[8];
  const float* Us_z = (const float*)d_in[9];
  const float* W_r  = (const float*)d_in[10];
  const float* U_r  = (const float*)d_in[11];
  const float* Us_r = (const float*)d_in[12];
  const float* W_hn = (const float*)d_in[13];
  const float* U_hn = (const float*)d_in[14];
  const float* Us_hn= (const float*)d_in[15];
  uint16_t* ws = (uint16_t*)d_ws;
  float* out = (float*)d_out;

  int rows = in_sizes[0] / D_IN;          // 262144
  prepack_kernel<<<(TOTAL_E + 255) / 256, 256, 0, stream>>>(
      Wi, Wh, W_z, U_z, Us_z, W_r, U_r, Us_r, W_hn, U_hn, Us_hn, bi, bh, ws);
  gru_fused<<<rows / BM, NTHREADS, 0, stream>>>(x, h_p, h_s, ws, out);
}